// Round 1
// baseline (248.985 us; speedup 1.0000x reference)
//
#include <hip/hip_runtime.h>
#include <stdint.h>

typedef __attribute__((ext_vector_type(8))) short short8;
typedef __attribute__((ext_vector_type(4))) float f32x4;

__device__ __forceinline__ unsigned short f2bf(float f) {
    union { float f; uint32_t u; } v; v.f = f;
    return (unsigned short)((v.u + 0x7FFFu + ((v.u >> 16) & 1u)) >> 16);
}

// Build W[j][k] (bf16, row-major 192x192): W[h*16+oc][g*16+ic] = kernel[cayley[inv[g],h]][oc][ic]
__global__ void build_w_kernel(const float* __restrict__ kern,
                               const int* __restrict__ cayley,
                               const int* __restrict__ inv,
                               unsigned short* __restrict__ Wbf) {
    int i = blockIdx.x * blockDim.x + threadIdx.x;
    if (i >= 192 * 192) return;
    int j = i / 192;
    int k = i - j * 192;
    int h = j >> 4, oc = j & 15;
    int g = k >> 4, ic = k & 15;
    int cidx = cayley[inv[g] * 12 + h];
    Wbf[i] = f2bf(kern[cidx * 256 + oc * 16 + ic]);
}

// out[n][j] = sum_k x[n][k] * W[j][k] + bias[j & 15]
// 4 waves/block, each wave: 64 rows (4 row-tiles of 16) x all 192 cols (12 col-tiles of 16).
__global__ __launch_bounds__(256) void gemm_kernel(
    const float* __restrict__ x,
    const unsigned short* __restrict__ Wbf,
    const float* __restrict__ bias,
    float* __restrict__ out, int nrows) {
  const int lane = threadIdx.x & 63;
  const int wid  = threadIdx.x >> 6;
  const int l15  = lane & 15;
  const int lhi  = lane >> 4;
  const int rowbase = (blockIdx.x * 4 + wid) * 64;
  if (rowbase + 64 > nrows) return;

  // A fragments: a[rt][c] = x[rowbase + rt*16 + (lane&15)][c*32 + (lane>>4)*8 .. +7] as bf16
  short8 a[4][6];
  #pragma unroll
  for (int rt = 0; rt < 4; ++rt) {
    const float* xr = x + (size_t)(rowbase + rt * 16 + l15) * 192 + lhi * 8;
    #pragma unroll
    for (int c = 0; c < 6; ++c) {
      f32x4 f0 = *(const f32x4*)(xr + c * 32);
      f32x4 f1 = *(const f32x4*)(xr + c * 32 + 4);
      short8 v;
      v[0] = (short)f2bf(f0[0]); v[1] = (short)f2bf(f0[1]);
      v[2] = (short)f2bf(f0[2]); v[3] = (short)f2bf(f0[3]);
      v[4] = (short)f2bf(f1[0]); v[5] = (short)f2bf(f1[1]);
      v[6] = (short)f2bf(f1[2]); v[7] = (short)f2bf(f1[3]);
      a[rt][c] = v;
    }
  }
  const float bval = bias[l15];

  for (int ct = 0; ct < 12; ++ct) {
    // B fragments: b[c] = W[ct*16 + (lane&15)][c*32 + (lane>>4)*8 .. +7]
    short8 b[6];
    const unsigned short* wr = Wbf + (size_t)(ct * 16 + l15) * 192 + lhi * 8;
    #pragma unroll
    for (int c = 0; c < 6; ++c) b[c] = *(const short8*)(wr + c * 32);
    #pragma unroll
    for (int rt = 0; rt < 4; ++rt) {
      f32x4 acc = {0.f, 0.f, 0.f, 0.f};
      #pragma unroll
      for (int c = 0; c < 6; ++c)
        acc = __builtin_amdgcn_mfma_f32_16x16x32_bf16(a[rt][c], b[c], acc, 0, 0, 0);
      // D: col = lane&15, row = (lane>>4)*4 + r
      float* orow = out + (size_t)(rowbase + rt * 16 + lhi * 4) * 192 + ct * 16 + l15;
      #pragma unroll
      for (int r = 0; r < 4; ++r)
        orow[(size_t)r * 192] = acc[r] + bval;
    }
  }
}

extern "C" void kernel_launch(void* const* d_in, const int* in_sizes, int n_in,
                              void* d_out, int out_size, void* d_ws, size_t ws_size,
                              hipStream_t stream) {
    const float* x      = (const float*)d_in[0];
    const float* kern   = (const float*)d_in[1];
    const float* bias   = (const float*)d_in[2];
    const int*   cayley = (const int*)d_in[3];
    const int*   inv    = (const int*)d_in[4];
    float* out = (float*)d_out;
    unsigned short* Wbf = (unsigned short*)d_ws;   // 192*192*2 = 73728 bytes

    const int nrows = in_sizes[0] / 192;

    build_w_kernel<<<(192 * 192 + 255) / 256, 256, 0, stream>>>(kern, cayley, inv, Wbf);

    const int nblocks = nrows / 256;   // 256 rows per block (4 waves x 64 rows)
    gemm_kernel<<<nblocks, 256, 0, stream>>>(x, Wbf, bias, out, nrows);
}